// Round 7
// baseline (267.896 us; speedup 1.0000x reference)
//
#include <hip/hip_runtime.h>
#include <math.h>

// Fused AntiAliasActivation: up2 (12-tap polyphase) -> snake -> down2 (12-tap)
// x: (B=16, C=512, T=4096) fp32, out: same shape.
//
// R8: two rows per block, interleaved in registers. Evidence: R3/R6/R7
// (three different memory structures) all land 84-89us with VALUBusy
// ~46%, HBM ~30% -- per-wave dependency stalls are the shared limiter
// (compiler register-minimized to 40 VGPR and serialized the unrolled
// rolling loop; fma/sin chains exposed). R8 keeps the hardware-verified
// R6 rolling core unchanged and doubles per-wave independent work:
// each thread computes W=16 outputs for TWO independent rows
// (row, row+half). ILP x2, MLP x2 (16 loads in flight), live set ~100
// floats so the compiler can't over-minimize registers. No LDS.
//
// Phase-plane formulation (hardware-verified R3..R7):
//   E[s] = act( 2*sum_m x[clamp(s-3+m)]*u[11-2m] )   (yact[2s])
//   O[s] = act( 2*sum_m x[clamp(s-2+m)]*u[10-2m] )   (yact[2s+1])
//   out[o] = sum_m E[o-2+m]*d[2m+1] + sum_m O[o-3+m]*d[2m]
//   act(y) = y + rb*sin(y*ea)^2
// Per thread (o0 = 16*t): f[j] = x[clamp(o0-8+j)], j=0..31; activation
// i=0..20: ev=E[o0-2+i], ov=O[o0-3+i], window f[i+3..i+8]; contribution
// of i to acc[r]: r in [i-5,i]&[0,15], taps d[2(i-r)+1] (E), d[2(i-r)]
// (O). Down-conv pad clamp: lo (t=0) skip i<2 + patch at i=2 with E[0];
// hi (t=255) override ev/ov with O[T-1] from i=18.

#define T_LEN 4096
#define NT    256
#define W     16                 // outputs per thread; NT*W == T_LEN

__global__ __launch_bounds__(NT, 2) void aa_act_kernel(
    const float* __restrict__ x,
    const float* __restrict__ alpha,
    const float* __restrict__ beta,
    const float* __restrict__ upf,
    const float* __restrict__ downf,
    float* __restrict__ out,
    int C, int half)
{
    const int t     = threadIdx.x;
    const int rowA  = blockIdx.x;
    const int rowB  = rowA + half;
    const int cA    = rowA % C;
    const int cB    = rowB % C;
    const int o0    = t * W;

    const float* __restrict__ xrA = x + (size_t)rowA * T_LEN;
    const float* __restrict__ xrB = x + (size_t)rowB * T_LEN;
    float* __restrict__ outA      = out + (size_t)rowA * T_LEN;
    float* __restrict__ outB      = out + (size_t)rowB * T_LEN;

    // Uniform filter taps. Prescale up-filter by 2 (UP factor) — exact.
    float ue[6], uo[6], d[12];
#pragma unroll
    for (int m = 0; m < 6; ++m) {
        ue[m] = 2.0f * upf[11 - 2 * m];
        uo[m] = 2.0f * upf[10 - 2 * m];
    }
#pragma unroll
    for (int i = 0; i < 12; ++i) d[i] = downf[i];

    const float eaA = __expf(alpha[cA]);
    const float rbA = 1.0f / (__expf(beta[cA]) + 1e-9f);
    const float eaB = __expf(alpha[cB]);
    const float rbB = 1.0f / (__expf(beta[cB]) + 1e-9f);

    const bool lo = (t == 0);
    const bool hi = (t == NT - 1);

    // ---- x[o0-8 .. o0+23] -> fA/fB[0..31], SROA-friendly ----
    float fA[32], fB[32];
    if (!lo && !hi) {
        const float4* pA = (const float4*)(xrA + o0 - 8);  // global: cast ok
        const float4* pB = (const float4*)(xrB + o0 - 8);
#pragma unroll
        for (int i = 0; i < 8; ++i) {
            float4 vA = pA[i];
            float4 vB = pB[i];
            fA[4*i+0] = vA.x; fA[4*i+1] = vA.y; fA[4*i+2] = vA.z; fA[4*i+3] = vA.w;
            fB[4*i+0] = vB.x; fB[4*i+1] = vB.y; fB[4*i+2] = vB.z; fB[4*i+3] = vB.w;
        }
    } else {
        // row-edge threads: scalar clamped loads (up-conv edge pad)
#pragma unroll
        for (int i = 0; i < 32; ++i) {
            int gi = min(max(o0 - 8 + i, 0), T_LEN - 1);
            fA[i] = xrA[gi];
            fB[i] = xrB[gi];
        }
    }

    float accA[W], accB[W];
#pragma unroll
    for (int r = 0; r < W; ++r) { accA[r] = 0.0f; accB[r] = 0.0f; }

    float RvA = 0.0f, RvB = 0.0f;   // O[T-1] capture (hi lane only)

#pragma unroll
    for (int i = 0; i < 21; ++i) {
        // ---- row A activation pair ----
        float yeA = fA[i + 3] * ue[0];
        yeA = fmaf(fA[i + 4], ue[1], yeA);
        yeA = fmaf(fA[i + 5], ue[2], yeA);
        yeA = fmaf(fA[i + 6], ue[3], yeA);
        yeA = fmaf(fA[i + 7], ue[4], yeA);
        yeA = fmaf(fA[i + 8], ue[5], yeA);
        float yoA = fA[i + 3] * uo[0];
        yoA = fmaf(fA[i + 4], uo[1], yoA);
        yoA = fmaf(fA[i + 5], uo[2], yoA);
        yoA = fmaf(fA[i + 6], uo[3], yoA);
        yoA = fmaf(fA[i + 7], uo[4], yoA);
        yoA = fmaf(fA[i + 8], uo[5], yoA);
        // ---- row B activation pair (independent chain) ----
        float yeB = fB[i + 3] * ue[0];
        yeB = fmaf(fB[i + 4], ue[1], yeB);
        yeB = fmaf(fB[i + 5], ue[2], yeB);
        yeB = fmaf(fB[i + 6], ue[3], yeB);
        yeB = fmaf(fB[i + 7], ue[4], yeB);
        yeB = fmaf(fB[i + 8], ue[5], yeB);
        float yoB = fB[i + 3] * uo[0];
        yoB = fmaf(fB[i + 4], uo[1], yoB);
        yoB = fmaf(fB[i + 5], uo[2], yoB);
        yoB = fmaf(fB[i + 6], uo[3], yoB);
        yoB = fmaf(fB[i + 7], uo[4], yoB);
        yoB = fmaf(fB[i + 8], uo[5], yoB);

        float seA = __sinf(yeA * eaA);
        float soA = __sinf(yoA * eaA);
        float seB = __sinf(yeB * eaB);
        float soB = __sinf(yoB * eaB);
        float evA = fmaf(rbA * seA, seA, yeA);
        float ovA = fmaf(rbA * soA, soA, yoA);
        float evB = fmaf(rbB * seB, seB, yeB);
        float ovB = fmaf(rbB * soB, soB, yoB);

        // ---- down-conv pad-clamp overrides (row edges) ----
        if (i == 18) {
            if (hi) { RvA = ovA; evA = ovA; RvB = ovB; evB = ovB; }
        }
        if (i >= 19) {
            if (hi) { evA = RvA; ovA = RvA; evB = RvB; ovB = RvB; }
        }
        if (i == 2) {
            if (lo) {
                accA[0] = fmaf(evA, d[0] + d[1] + d[2] + d[3], accA[0]);
                accA[1] = fmaf(evA, d[0] + d[1], accA[1]);
                ovA = evA;
                accB[0] = fmaf(evB, d[0] + d[1] + d[2] + d[3], accB[0]);
                accB[1] = fmaf(evB, d[0] + d[1], accB[1]);
                ovB = evB;
            }
        }

        // ---- consume into accumulators: r in [i-5, i] & [0, 15] ----
        const int rlo = (i - 5 > 0) ? (i - 5) : 0;
        const int rhi = (i < W - 1) ? i : (W - 1);
        if (i < 2) {
            if (!lo) {
#pragma unroll
                for (int r = rlo; r <= rhi; ++r) {
                    accA[r] = fmaf(evA, d[2 * (i - r) + 1],
                              fmaf(ovA, d[2 * (i - r)], accA[r]));
                    accB[r] = fmaf(evB, d[2 * (i - r) + 1],
                              fmaf(ovB, d[2 * (i - r)], accB[r]));
                }
            }
        } else {
#pragma unroll
            for (int r = rlo; r <= rhi; ++r) {
                accA[r] = fmaf(evA, d[2 * (i - r) + 1],
                          fmaf(ovA, d[2 * (i - r)], accA[r]));
                accB[r] = fmaf(evB, d[2 * (i - r) + 1],
                          fmaf(ovB, d[2 * (i - r)], accB[r]));
            }
        }
    }

    // ---- stores: compose float4 from components (SROA-friendly) ----
    float4* poA = (float4*)(outA + o0);          // global: cast ok
    float4* poB = (float4*)(outB + o0);
    poA[0] = make_float4(accA[ 0], accA[ 1], accA[ 2], accA[ 3]);
    poA[1] = make_float4(accA[ 4], accA[ 5], accA[ 6], accA[ 7]);
    poA[2] = make_float4(accA[ 8], accA[ 9], accA[10], accA[11]);
    poA[3] = make_float4(accA[12], accA[13], accA[14], accA[15]);
    poB[0] = make_float4(accB[ 0], accB[ 1], accB[ 2], accB[ 3]);
    poB[1] = make_float4(accB[ 4], accB[ 5], accB[ 6], accB[ 7]);
    poB[2] = make_float4(accB[ 8], accB[ 9], accB[10], accB[11]);
    poB[3] = make_float4(accB[12], accB[13], accB[14], accB[15]);
}

extern "C" void kernel_launch(void* const* d_in, const int* in_sizes, int n_in,
                              void* d_out, int out_size, void* d_ws, size_t ws_size,
                              hipStream_t stream) {
    const float* x     = (const float*)d_in[0];
    const float* alpha = (const float*)d_in[1];
    const float* beta  = (const float*)d_in[2];
    const float* upf   = (const float*)d_in[3];
    const float* downf = (const float*)d_in[4];
    float* out = (float*)d_out;

    const int C    = in_sizes[1];             // 512
    const int rows = in_sizes[0] / T_LEN;     // B*C = 8192
    const int half = rows / 2;                // 4096

    dim3 grid(half), block(NT);
    hipLaunchKernelGGL(aa_act_kernel, grid, block, 0, stream,
                       x, alpha, beta, upf, downf, out, C, half);
}

// Round 9
// 230.348 us; speedup vs baseline: 1.1630x; 1.1630x over previous
//
#include <hip/hip_runtime.h>
#include <math.h>

// Fused AntiAliasActivation: up2 (12-tap polyphase) -> snake -> down2 (12-tap)
// x: (B=16, C=512, T=4096) fp32, out: same shape.
//
// R9: W=8 outputs/thread (was 16) -> 2x wave count, ~50-float live set,
// VGPR<=64 -> 8 waves/SIMD residency. Evidence: dur tracks occupancy
// monotonically across R3/R6/R7/R8 (77%->89us w/ conflicts, 50%->83.5,
// 46%->85, 26%->111); R8 (ILP x2, waves /2) REGRESSED -> kernel is
// latency-bound (fma/v_sin/VMEM chains), cured by TLP not ILP.
// Redundancy cost: 13 activation pairs per 8 outputs (1.63x vs 1.31x at
// W=16, +24% VALU) -- affordable at VALUBusy 37%.
//
// Phase-plane formulation (hardware-verified R3..R8):
//   E[s] = act( 2*sum_m x[clamp(s-3+m)]*u[11-2m] )   (yact[2s])
//   O[s] = act( 2*sum_m x[clamp(s-2+m)]*u[10-2m] )   (yact[2s+1])
//   out[o] = sum_m E[o-2+m]*d[2m+1] + sum_m O[o-3+m]*d[2m]
//   act(y) = y + rb*sin(y*ea)^2
// Per thread (o0 = global offset, W=8): f[j] = x[clamp(o0-8+j)],
// j=0..23 (6 aligned float4); activation i=0..12: ev=E[o0-2+i],
// ov=O[o0-3+i], window f[i+3..i+8]; contribution of i to acc[r]:
// r in [i-5,i]&[0,7], taps d[2(i-r)+1] (E), d[2(i-r)] (O).
// Row-edge clamps: lo thread (o0==0): skip i<2, patch acc[0]+=E[0]*
// (d0+d1+d2+d3), acc[1]+=E[0]*(d0+d1), ov:=ev at i=2 (index-independent
// constants, same as R6). hi thread (o0==T-8): E[T] first appears at
// i = (T+2)-o0 = 10, and O[T-1] is ov at that same i -> Rv=ov, ev:=ov
// at i=10; ev=ov:=Rv for i>=11.

#define T_LEN 4096
#define NT    256
#define W     8                  // outputs per thread
#define NA    13                 // activation pairs per thread (W+5)

__global__ __launch_bounds__(NT, 4) void aa_act_kernel(
    const float* __restrict__ x,
    const float* __restrict__ alpha,
    const float* __restrict__ beta,
    const float* __restrict__ upf,
    const float* __restrict__ downf,
    float* __restrict__ out,
    int C)
{
    const int t   = threadIdx.x;
    const int blk = blockIdx.x;
    const int row = blk >> 1;                  // 2 blocks per row
    const int o0  = ((blk & 1) << 11) | (t << 3);
    const int c   = row % C;

    const float* __restrict__ xr = x + (size_t)row * T_LEN;
    float* __restrict__ outr     = out + (size_t)row * T_LEN;

    // Uniform filter taps. Prescale up-filter by 2 (UP factor) — exact.
    float ue[6], uo[6], d[12];
#pragma unroll
    for (int m = 0; m < 6; ++m) {
        ue[m] = 2.0f * upf[11 - 2 * m];
        uo[m] = 2.0f * upf[10 - 2 * m];
    }
#pragma unroll
    for (int i = 0; i < 12; ++i) d[i] = downf[i];

    const float ea = __expf(alpha[c]);
    const float rb = 1.0f / (__expf(beta[c]) + 1e-9f);

    const bool lo = (o0 == 0);
    const bool hi = (o0 == T_LEN - W);

    // ---- x[o0-8 .. o0+15] -> f[0..23], SROA-friendly ----
    float f[24];
    if (!lo && !hi) {
        const float4* p = (const float4*)(xr + o0 - 8);  // global: cast ok
#pragma unroll
        for (int i = 0; i < 6; ++i) {
            float4 v = p[i];
            f[4*i+0] = v.x; f[4*i+1] = v.y; f[4*i+2] = v.z; f[4*i+3] = v.w;
        }
    } else {
        // row-edge threads: scalar clamped loads (up-conv edge pad)
#pragma unroll
        for (int i = 0; i < 24; ++i)
            f[i] = xr[min(max(o0 - 8 + i, 0), T_LEN - 1)];
    }

    float acc[W];
#pragma unroll
    for (int r = 0; r < W; ++r) acc[r] = 0.0f;

    float Rv = 0.0f;   // O[T-1] capture (hi lane only)

#pragma unroll
    for (int i = 0; i < NA; ++i) {
        // activation pair at rolling index i
        float ye = f[i + 3] * ue[0];
        ye = fmaf(f[i + 4], ue[1], ye);
        ye = fmaf(f[i + 5], ue[2], ye);
        ye = fmaf(f[i + 6], ue[3], ye);
        ye = fmaf(f[i + 7], ue[4], ye);
        ye = fmaf(f[i + 8], ue[5], ye);
        float yo = f[i + 3] * uo[0];
        yo = fmaf(f[i + 4], uo[1], yo);
        yo = fmaf(f[i + 5], uo[2], yo);
        yo = fmaf(f[i + 6], uo[3], yo);
        yo = fmaf(f[i + 7], uo[4], yo);
        yo = fmaf(f[i + 8], uo[5], yo);
        float se = __sinf(ye * ea);
        float so = __sinf(yo * ea);
        float ev = fmaf(rb * se, se, ye);
        float ov = fmaf(rb * so, so, yo);

        // ---- down-conv pad-clamp overrides (row edges) ----
        if (i == 10) {
            if (hi) { Rv = ov; ev = ov; }          // E[T] := O[T-1]
        }
        if (i >= 11) {
            if (hi) { ev = Rv; ov = Rv; }          // E/O[>T] := O[T-1]
        }
        if (i == 2) {
            if (lo) {
                // ev == E[0]; patch the skipped i=0,1 contributions
                acc[0] = fmaf(ev, d[0] + d[1] + d[2] + d[3], acc[0]);
                acc[1] = fmaf(ev, d[0] + d[1], acc[1]);
                ov = ev;                            // O[-1] := E[0]
            }
        }

        // ---- consume into accumulators: r in [i-5, i] & [0, W-1] ----
        const int rlo = (i - 5 > 0) ? (i - 5) : 0;
        const int rhi = (i < W - 1) ? i : (W - 1);
        if (i < 2) {
            if (!lo) {
#pragma unroll
                for (int r = rlo; r <= rhi; ++r)
                    acc[r] = fmaf(ev, d[2 * (i - r) + 1],
                             fmaf(ov, d[2 * (i - r)], acc[r]));
            }
        } else {
#pragma unroll
            for (int r = rlo; r <= rhi; ++r)
                acc[r] = fmaf(ev, d[2 * (i - r) + 1],
                         fmaf(ov, d[2 * (i - r)], acc[r]));
        }
    }

    // ---- store: compose float4 from components (SROA-friendly) ----
    float4* po = (float4*)(outr + o0);           // global: cast ok
    po[0] = make_float4(acc[0], acc[1], acc[2], acc[3]);
    po[1] = make_float4(acc[4], acc[5], acc[6], acc[7]);
}

extern "C" void kernel_launch(void* const* d_in, const int* in_sizes, int n_in,
                              void* d_out, int out_size, void* d_ws, size_t ws_size,
                              hipStream_t stream) {
    const float* x     = (const float*)d_in[0];
    const float* alpha = (const float*)d_in[1];
    const float* beta  = (const float*)d_in[2];
    const float* upf   = (const float*)d_in[3];
    const float* downf = (const float*)d_in[4];
    float* out = (float*)d_out;

    const int C    = in_sizes[1];             // 512
    const int rows = in_sizes[0] / T_LEN;     // B*C = 8192

    dim3 grid(rows * 2), block(NT);
    hipLaunchKernelGGL(aa_act_kernel, grid, block, 0, stream,
                       x, alpha, beta, upf, downf, out, C);
}